// Round 3
// baseline (963.112 us; speedup 1.0000x reference)
//
#include <hip/hip_runtime.h>
#include <hip/hip_bf16.h>

typedef unsigned short u16;
typedef float floatx4 __attribute__((ext_vector_type(4)));
typedef __bf16 bf16x8 __attribute__((ext_vector_type(8)));
typedef _Float16 f16x8 __attribute__((ext_vector_type(8)));

#define NN 8192
#define DD 512
#define NPARTS 8
#define JCHUNK 1024   // NN / NPARTS

__device__ __forceinline__ u16 f2bf(float f) {
    __hip_bfloat16 h = __float2bfloat16(f);   // RNE
    return __builtin_bit_cast(u16, h);
}
__device__ __forceinline__ float bf2f(u16 u) {
    unsigned v = (unsigned)u << 16;
    return __builtin_bit_cast(float, v);
}
__device__ __forceinline__ u16 f2h(float f) {
    _Float16 h = (_Float16)f;                 // RNE
    return __builtin_bit_cast(u16, h);
}
__device__ __forceinline__ float h2f(u16 u) {
    _Float16 h = __builtin_bit_cast(_Float16, u);
    return (float)h;
}

// ---------------------------------------------------------------------------
// Projection GEMM with hi/lo bf16 split (fp32-accurate accumulator), output
// stored as SINGLE fp16 (storage rel err 2^-12 — below the noise floor).
// z=0: Q = x1@q (row-major fp16), z=1: K = x2@k, z=2: VT = (x1@v)^T
// ---------------------------------------------------------------------------
__global__ __launch_bounds__(256, 2)
void proj_kernel(const float* __restrict__ x1, const float* __restrict__ x2,
                 const float* __restrict__ qw, const float* __restrict__ kw,
                 const float* __restrict__ vw,
                 u16* __restrict__ Qf, u16* __restrict__ Kf, u16* __restrict__ VT)
{
    const int which = blockIdx.z;
    const float* A = (which == 1) ? x2 : x1;
    const float* W = (which == 0) ? qw : (which == 1 ? kw : vw);

    __shared__ u16 Ash[128 * 40], Asl[128 * 40];  // [m][k]
    __shared__ u16 Wsh[128 * 40], Wsl[128 * 40];  // [n][k] (W transposed)

    const int tid  = threadIdx.x;
    const int lane = tid & 63;
    const int wave = tid >> 6;
    const int l15  = lane & 15;
    const int quad = lane >> 4;
    const int wm   = (wave & 1) * 64;
    const int wn   = (wave >> 1) * 64;
    const int m0   = blockIdx.x * 128;
    const int n0   = blockIdx.y * 128;

    floatx4 acc[4][4] = {};

    for (int k0 = 0; k0 < DD; k0 += 32) {
        __syncthreads();
        {   // Stage A tile: 128 x 32 fp32 -> hi/lo bf16 [m][k]
            const int cg = (tid & 7) * 4;
            for (int i = 0; i < 4; i++) {
                const int row = (tid >> 3) + i * 32;
                float4 f = *(const float4*)&A[(size_t)(m0 + row) * DD + k0 + cg];
                u16 hx = f2bf(f.x), hy = f2bf(f.y), hz = f2bf(f.z), hw = f2bf(f.w);
                uint2 ph, pl;
                ph.x = ((unsigned)hy << 16) | hx;
                ph.y = ((unsigned)hw << 16) | hz;
                pl.x = ((unsigned)f2bf(f.y - bf2f(hy)) << 16) | f2bf(f.x - bf2f(hx));
                pl.y = ((unsigned)f2bf(f.w - bf2f(hw)) << 16) | f2bf(f.z - bf2f(hz));
                *(uint2*)&Ash[row * 40 + cg] = ph;
                *(uint2*)&Asl[row * 40 + cg] = pl;
            }
        }
        {   // Stage W tile: 32(k) x 128(n) -> hi/lo [n][k]
            const int kr = tid & 31;
            const int g  = tid >> 5;
            for (int i = 0; i < 4; i++) {
                const int n = (g + i * 8) * 4;
                float4 f = *(const float4*)&W[(size_t)(k0 + kr) * DD + n0 + n];
                float e[4] = {f.x, f.y, f.z, f.w};
                for (int j = 0; j < 4; j++) {
                    u16 h = f2bf(e[j]);
                    Wsh[(n + j) * 40 + kr] = h;
                    Wsl[(n + j) * 40 + kr] = f2bf(e[j] - bf2f(h));
                }
            }
        }
        __syncthreads();

        bf16x8 ah[4], al[4], bh[4], bl[4];
        for (int mi = 0; mi < 4; mi++) {
            ah[mi] = *(const bf16x8*)&Ash[(wm + mi * 16 + l15) * 40 + quad * 8];
            al[mi] = *(const bf16x8*)&Asl[(wm + mi * 16 + l15) * 40 + quad * 8];
        }
        for (int ni = 0; ni < 4; ni++) {
            bh[ni] = *(const bf16x8*)&Wsh[(wn + ni * 16 + l15) * 40 + quad * 8];
            bl[ni] = *(const bf16x8*)&Wsl[(wn + ni * 16 + l15) * 40 + quad * 8];
        }
        for (int mi = 0; mi < 4; mi++)
            for (int ni = 0; ni < 4; ni++) {
                acc[mi][ni] = __builtin_amdgcn_mfma_f32_16x16x32_bf16(ah[mi], bh[ni], acc[mi][ni], 0, 0, 0);
                acc[mi][ni] = __builtin_amdgcn_mfma_f32_16x16x32_bf16(ah[mi], bl[ni], acc[mi][ni], 0, 0, 0);
                acc[mi][ni] = __builtin_amdgcn_mfma_f32_16x16x32_bf16(al[mi], bh[ni], acc[mi][ni], 0, 0, 0);
            }
    }

    // Epilogue: C/D layout col = lane&15, row = quad*4 + reg; store fp16
    for (int mi = 0; mi < 4; mi++)
        for (int ni = 0; ni < 4; ni++)
            for (int r = 0; r < 4; r++) {
                const int row = m0 + wm + mi * 16 + quad * 4 + r;
                const int col = n0 + wn + ni * 16 + l15;
                const u16 hv = f2h(acc[mi][ni][r]);
                if (which == 0)      Qf[(size_t)row * DD + col] = hv;
                else if (which == 1) Kf[(size_t)row * DD + col] = hv;
                else                 VT[(size_t)col * NN + row] = hv;
            }
}

// ---------------------------------------------------------------------------
// Flash attention partials, fp16 MFMA. Grid (128 row-blocks, 8 j-parts),
// 256 thr. Block: 64 Q rows (16/wave), BN=64 K rows/iter, D=512 in per-wave
// accumulators (128 VGPR). LDS: K-chunk and V-chunk share one buffer
// (disjoint barrier-separated phases) -> 27.4 KB -> 4 blocks/CU.
// ---------------------------------------------------------------------------
__global__ __launch_bounds__(256, 4)
void attn_kernel(const u16* __restrict__ Qf, const u16* __restrict__ Kf,
                 const u16* __restrict__ VT,
                 u16* __restrict__ Opart, float* __restrict__ Mp,
                 float* __restrict__ Lp)
{
    const int rb   = blockIdx.x;
    const int part = blockIdx.y;
    const int tid  = threadIdx.x;
    const int lane = tid & 63;
    const int wave = tid >> 6;
    const int l15  = lane & 15;
    const int quad = lane >> 4;

    // Union buffer: QK phase uses it as K chunk [j=64][d=128] stride 136
    //               PV phase uses it as V^T chunk [d=128][j=64] stride 72
    __shared__ u16 KVs[128 * 72];           // 18432 B, covers both (K needs 8704 u16)
    __shared__ u16 Ps[4][16 * 68];          // per-wave P [qrow][j], stride 68 (bank-clean writes)

    const int q0 = rb * 64 + wave * 16;     // wave's Q rows

    floatx4 o[32] = {};                     // O: 16 rows x 512 cols (C-layout)
    float m_run[4], l_run[4];
    for (int r = 0; r < 4; r++) { m_run[r] = -1e30f; l_run[r] = 0.f; }

    const int j_begin = part * JCHUNK;
    const int j_end   = j_begin + JCHUNK;

    for (int j0 = j_begin; j0 < j_end; j0 += 64) {
        // ---- S = Q K^T over this 64-row K tile (full D=512) ----
        floatx4 s[4] = {};
        for (int dc = 0; dc < 4; dc++) {
            __syncthreads();
            {   // stage K rows j0..j0+64, cols dc*128..+128
                const int dd = (tid & 15) * 8;
                for (int i = 0; i < 4; i++) {
                    const int jj = (tid >> 4) + i * 16;
                    *(uint4*)&KVs[jj * 136 + dd] =
                        *(const uint4*)&Kf[(size_t)(j0 + jj) * DD + dc * 128 + dd];
                }
            }
            __syncthreads();
            f16x8 qf[4];
            for (int ks = 0; ks < 4; ks++)
                qf[ks] = *(const f16x8*)&Qf[(size_t)(q0 + l15) * DD + dc * 128 + ks * 32 + quad * 8];
            for (int ks = 0; ks < 4; ks++)
                for (int nt = 0; nt < 4; nt++) {
                    f16x8 b = *(const f16x8*)&KVs[(nt * 16 + l15) * 136 + ks * 32 + quad * 8];
                    s[nt] = __builtin_amdgcn_mfma_f32_16x16x32_f16(qf[ks], b, s[nt], 0, 0, 0);
                }
        }

        // ---- leaky_relu + online softmax ----
        for (int nt = 0; nt < 4; nt++)
            for (int r = 0; r < 4; r++) {
                float x = s[nt][r];
                s[nt][r] = x >= 0.f ? x : 0.01f * x;
            }
        float mt[4];
        for (int r = 0; r < 4; r++)
            mt[r] = fmaxf(fmaxf(s[0][r], s[1][r]), fmaxf(s[2][r], s[3][r]));
        for (int off = 1; off < 16; off <<= 1)
            for (int r = 0; r < 4; r++)
                mt[r] = fmaxf(mt[r], __shfl_xor(mt[r], off));

        float alpha[4];
        for (int r = 0; r < 4; r++) {
            const float mnew = fmaxf(m_run[r], mt[r]);
            alpha[r] = __expf(m_run[r] - mnew);
            m_run[r] = mnew;
        }
        float ls[4] = {0.f, 0.f, 0.f, 0.f};
        u16 pv[4][4];
        for (int nt = 0; nt < 4; nt++)
            for (int r = 0; r < 4; r++) {
                const float p = __expf(s[nt][r] - m_run[r]);
                ls[r] += p;
                pv[nt][r] = f2h(p);
            }
        for (int off = 1; off < 16; off <<= 1)
            for (int r = 0; r < 4; r++)
                ls[r] += __shfl_xor(ls[r], off);
        for (int r = 0; r < 4; r++)
            l_run[r] = l_run[r] * alpha[r] + ls[r];
        // Rescale O only when some row's max actually moved (first iter always)
        const bool need = (alpha[0] != 1.f) | (alpha[1] != 1.f) |
                          (alpha[2] != 1.f) | (alpha[3] != 1.f);
        if (__any(need))
            for (int i = 0; i < 32; i++)
                for (int r = 0; r < 4; r++)
                    o[i][r] *= alpha[r];

        // ---- P: C-layout -> A-layout via per-wave LDS (same-wave, waitcnt only) ----
        for (int nt = 0; nt < 4; nt++)
            for (int r = 0; r < 4; r++)
                Ps[wave][(quad * 4 + r) * 68 + nt * 16 + l15] = pv[nt][r];
        asm volatile("s_waitcnt lgkmcnt(0)" ::: "memory");
        f16x8 pf[2];
        for (int ks = 0; ks < 2; ks++)
            pf[ks] = *(const f16x8*)&Ps[wave][l15 * 68 + ks * 32 + quad * 8];

        // ---- O += P @ V ----
        for (int dc = 0; dc < 4; dc++) {
            __syncthreads();
            {   // stage V^T rows dc*128..+128, cols j0..j0+64
                const int cg = (tid & 7) * 8;
                for (int i = 0; i < 4; i++) {
                    const int dr = (tid >> 3) + i * 32;
                    *(uint4*)&KVs[dr * 72 + cg] =
                        *(const uint4*)&VT[(size_t)(dc * 128 + dr) * NN + j0 + cg];
                }
            }
            __syncthreads();
            for (int nt2 = 0; nt2 < 8; nt2++) {
                f16x8 b0 = *(const f16x8*)&KVs[(nt2 * 16 + l15) * 72 + quad * 8];
                f16x8 b1 = *(const f16x8*)&KVs[(nt2 * 16 + l15) * 72 + 32 + quad * 8];
                o[dc * 8 + nt2] = __builtin_amdgcn_mfma_f32_16x16x32_f16(pf[0], b0, o[dc * 8 + nt2], 0, 0, 0);
                o[dc * 8 + nt2] = __builtin_amdgcn_mfma_f32_16x16x32_f16(pf[1], b1, o[dc * 8 + nt2], 0, 0, 0);
            }
        }
    }

    // ---- write partials (fp16 un-normalized O + fp32 m,l) ----
    for (int i = 0; i < 32; i++)
        for (int r = 0; r < 4; r++) {
            const int row = q0 + quad * 4 + r;
            const int col = i * 16 + l15;
            Opart[((size_t)part * NN + row) * DD + col] = f2h(o[i][r]);
        }
    if (l15 == 0)
        for (int r = 0; r < 4; r++) {
            const int row = q0 + quad * 4 + r;
            Mp[part * NN + row] = m_run[r];
            Lp[part * NN + row] = l_run[r];
        }
}

// ---------------------------------------------------------------------------
// Combine NPARTS j-partials: out = sum_p w_p O_p / sum_p w_p l_p,
// w_p = exp(m_p - M)
// ---------------------------------------------------------------------------
__global__ __launch_bounds__(256)
void combine_kernel(const u16* __restrict__ Opart, const float* __restrict__ Mp,
                    const float* __restrict__ Lp, float* __restrict__ out)
{
    const int row = blockIdx.x;
    const int tid = threadIdx.x;
    float m[NPARTS], l[NPARTS];
    float M = -1e30f;
    for (int p = 0; p < NPARTS; p++) {
        m[p] = Mp[p * NN + row];
        l[p] = Lp[p * NN + row];
        M = fmaxf(M, m[p]);
    }
    float w[NPARTS], L = 0.f;
    for (int p = 0; p < NPARTS; p++) { w[p] = __expf(m[p] - M); L += w[p] * l[p]; }
    const float inv = 1.f / L;
    for (int d = tid; d < DD; d += 256) {
        float acc = 0.f;
        for (int p = 0; p < NPARTS; p++)
            acc += w[p] * h2f(Opart[((size_t)p * NN + row) * DD + d]);
        out[(size_t)row * DD + d] = acc * inv;
    }
}

// ---------------------------------------------------------------------------
extern "C" void kernel_launch(void* const* d_in, const int* in_sizes, int n_in,
                              void* d_out, int out_size, void* d_ws, size_t ws_size,
                              hipStream_t stream)
{
    const float* x1 = (const float*)d_in[0];
    const float* x2 = (const float*)d_in[1];
    const float* qw = (const float*)d_in[2];
    const float* kw = (const float*)d_in[3];
    const float* vw = (const float*)d_in[4];
    float* out = (float*)d_out;

    // workspace: Qf|Kf|VT (8MB each fp16) | Opart 64MB fp16 | Mp | Lp  (~88.5MB)
    u16* Qf = (u16*)d_ws;
    u16* Kf = Qf + (size_t)NN * DD;
    u16* VT = Kf + (size_t)NN * DD;
    u16* Opart = VT + (size_t)NN * DD;
    float* Mp = (float*)(Opart + (size_t)NPARTS * NN * DD);
    float* Lp = Mp + NPARTS * NN;

    proj_kernel<<<dim3(64, 4, 3), 256, 0, stream>>>(x1, x2, qw, kw, vw, Qf, Kf, VT);
    attn_kernel<<<dim3(128, NPARTS), 256, 0, stream>>>(Qf, Kf, VT, Opart, Mp, Lp);
    combine_kernel<<<NN, 256, 0, stream>>>(Opart, Mp, Lp, out);
}